// Round 9
// baseline (224.024 us; speedup 1.0000x reference)
//
#include <hip/hip_runtime.h>
#include <math.h>
#include <stdint.h>

#define B_SZ   2
#define N_PTS  8192
#define IN_DIM 64
#define D_IN   70          // 64 features + 6 geom
#define ODIM   128
#define NQ_ALL (B_SZ * N_PTS)
#define RADIUS_F 0.02f

#define GDIM  32
#define NCELL (GDIM * GDIM * GDIM)
#define HCELL 0.03125f     // 1/32, exact in f32

#define SUP     4                       // base cells per supercell axis (exact tiling)
#define NSUP_AX 8
#define NSUPER  (NSUP_AX * NSUP_AX * NSUP_AX)   // 512
#define NSPLIT  4                       // blocks per supercell (query-slot split)
#define SCAP    352                     // staged halo capacity
#define LCAP    12                      // per-lane collect buffer (16 lanes/query)
#define LSTR    (LCAP + 1)              // padded stride (13 u64 -> spread banks)
#define MAXROWS 100                     // 10x10 halo (z,y) rows max

typedef unsigned long long u64;

// ---------------------------------------------------------------------------
__device__ __forceinline__ void insert11(u64 (&best)[11], u64 key) {
#pragma unroll
  for (int j = 10; j >= 1; --j) {
    u64 hi = (best[j - 1] > key) ? best[j - 1] : key;
    best[j] = (best[j] < hi) ? best[j] : hi;
  }
  best[0] = (best[0] < key) ? best[0] : key;
}
__device__ __forceinline__ void insert10(u64 (&best)[10], u64 key) {
#pragma unroll
  for (int j = 9; j >= 1; --j) {
    u64 hi = (best[j - 1] > key) ? best[j - 1] : key;
    best[j] = (best[j] < hi) ? best[j] : hi;
  }
  best[0] = (best[0] < key) ? best[0] : key;
}

// exact f32 helpers matching the reference's op order (no contraction)
__device__ __forceinline__ float sq3(float x, float y, float z) {
  return __fadd_rn(__fadd_rn(__fmul_rn(x, x), __fmul_rn(y, y)), __fmul_rn(z, z));
}

__device__ __forceinline__ int cellOf(float v) {
  int c = (int)(v * 32.0f);            // v*32 is exact (power-of-2 scale)
  return min(max(c, 0), GDIM - 1);
}

// shared epilogue: covariance over the 10 NN (exact f64) + eigen + geometry
__device__ __forceinline__ void geom_epilogue(const float* __restrict__ P,
                                              const int (&idxs)[10], float dens,
                                              float px, float py, float pz,
                                              float4 ctr, float* __restrict__ g) {
  double c00 = 0, c01 = 0, c02 = 0, c11 = 0, c12 = 0, c22 = 0;
#pragma unroll
  for (int j = 0; j < 10; ++j) {
    const int idx = idxs[j];
    const float nx = P[3 * idx + 0], ny = P[3 * idx + 1], nz = P[3 * idx + 2];
    const float ex = __fsub_rn(nx, px);
    const float ey = __fsub_rn(ny, py);
    const float ez = __fsub_rn(nz, pz);
    c00 += (double)ex * ex; c01 += (double)ex * ey; c02 += (double)ex * ez;
    c11 += (double)ey * ey; c12 += (double)ey * ez; c22 += (double)ez * ez;
  }
  const double a00 = c00 / 10.0, a01 = c01 / 10.0, a02 = c02 / 10.0;
  const double a11 = c11 / 10.0, a12 = c12 / 10.0, a22 = c22 / 10.0;

  double p1 = a01 * a01 + a02 * a02 + a12 * a12;
  double qq = (a00 + a11 + a22) / 3.0;
  double p2 = (a00 - qq) * (a00 - qq) + (a11 - qq) * (a11 - qq) +
              (a22 - qq) * (a22 - qq) + 2.0 * p1;
  double ev0, ev2;
  if (p2 <= 1e-60) {
    ev0 = ev2 = qq;
  } else {
    double p = sqrt(p2 / 6.0);
    double invp = 1.0 / p;
    double b00 = (a00 - qq) * invp, b11 = (a11 - qq) * invp, b22 = (a22 - qq) * invp;
    double b01 = a01 * invp, b02 = a02 * invp, b12 = a12 * invp;
    double detB = b00 * (b11 * b22 - b12 * b12) - b01 * (b01 * b22 - b12 * b02) +
                  b02 * (b01 * b12 - b11 * b02);
    double r = 0.5 * detB;
    r = fmin(1.0, fmax(-1.0, r));
    double phi = acos(r) / 3.0;
    ev2 = qq + 2.0 * p * cos(phi);
    ev0 = qq + 2.0 * p * cos(phi + 2.0943951023931953);  // +2*pi/3
  }
  const float curv = (float)(ev0 / (ev2 + 1e-08));

  const bool on = ctr.w > 0.0f;
  const float rx = __fsub_rn(px, ctr.x);
  const float ry = __fsub_rn(py, ctr.y);
  const float rz = __fsub_rn(pz, ctr.z);
  const float dist_c = sqrtf(sq3(rx, ry, rz));
  const float horiz  = sqrtf(__fadd_rn(__fmul_rn(rx, rx), __fmul_rn(ry, ry)));
  const float rad    = atan2f(ry, rx);

  g[0] = on ? dist_c : 0.0f;
  g[1] = on ? rz : 0.0f;
  g[2] = on ? horiz : 0.0f;
  g[3] = on ? dens : 0.0f;
  g[4] = on ? curv : 0.0f;
  g[5] = on ? rad : 0.0f;
}

// ---------------------------------------------------------------------------
// k_build: fused grid count + masked-centroid partial reduction.
__global__ __launch_bounds__(256) void k_build(const float* __restrict__ points,
                                               const int* __restrict__ mask,
                                               int* __restrict__ count,
                                               double* __restrict__ ctrAcc) {
  const int t = blockIdx.x * 256 + threadIdx.x;
  const int b = t >> 13;
  const int i = t & (N_PTS - 1);
  const float* P = points + (size_t)b * N_PTS * 3;
  const float x = P[3 * i + 0], y = P[3 * i + 1], z = P[3 * i + 2];
  atomicAdd(&count[b * NCELL + (cellOf(z) * GDIM + cellOf(y)) * GDIM + cellOf(x)], 1);

  const bool m = mask[b * N_PTS + i] != 0;
  double vx = m ? (double)x : 0.0, vy = m ? (double)y : 0.0;
  double vz = m ? (double)z : 0.0, vc = m ? 1.0 : 0.0;
#pragma unroll
  for (int s = 1; s < 64; s <<= 1) {
    vx += __shfl_xor(vx, s); vy += __shfl_xor(vy, s);
    vz += __shfl_xor(vz, s); vc += __shfl_xor(vc, s);
  }
  __shared__ double sh[4][4];
  const int w = threadIdx.x >> 6;
  if ((threadIdx.x & 63) == 0) { sh[0][w] = vx; sh[1][w] = vy; sh[2][w] = vz; sh[3][w] = vc; }
  __syncthreads();
  if (threadIdx.x == 0) {
    atomicAdd(&ctrAcc[b * 4 + 0], sh[0][0] + sh[0][1] + sh[0][2] + sh[0][3]);
    atomicAdd(&ctrAcc[b * 4 + 1], sh[1][0] + sh[1][1] + sh[1][2] + sh[1][3]);
    atomicAdd(&ctrAcc[b * 4 + 2], sh[2][0] + sh[2][1] + sh[2][2] + sh[2][3]);
    atomicAdd(&ctrAcc[b * 4 + 3], sh[3][0] + sh[3][1] + sh[3][2] + sh[3][3]);
  }
}

// one block of 1024 threads per batch; exclusive scan of 32768 counts.
__global__ __launch_bounds__(1024) void k_scan(const int* __restrict__ count,
                                               int* __restrict__ start,
                                               int* __restrict__ cur,
                                               const double* __restrict__ ctrAcc,
                                               float* __restrict__ centerOut) {
  const int b = blockIdx.x;
  const int t = threadIdx.x;
  if (t == 0) {
    const float cf = (float)ctrAcc[b * 4 + 3];
    const float div = fmaxf(cf, 1.0f);
    centerOut[b * 4 + 0] = (float)ctrAcc[b * 4 + 0] / div;
    centerOut[b * 4 + 1] = (float)ctrAcc[b * 4 + 1] / div;
    centerOut[b * 4 + 2] = (float)ctrAcc[b * 4 + 2] / div;
    centerOut[b * 4 + 3] = (cf > 0.0f) ? 1.0f : 0.0f;
  }
  int c[32]; int sum = 0;
#pragma unroll
  for (int j = 0; j < 32; ++j) { c[j] = count[b * NCELL + t * 32 + j]; sum += c[j]; }
  __shared__ int s[1024];
  s[t] = sum;
  __syncthreads();
  for (int off = 1; off < 1024; off <<= 1) {
    int v = (t >= off) ? s[t - off] : 0;
    __syncthreads();
    if (t >= off) s[t] += v;
    __syncthreads();
  }
  int excl = (t > 0) ? s[t - 1] : 0;
#pragma unroll
  for (int j = 0; j < 32; ++j) {
    start[b * (NCELL + 1) + t * 32 + j] = excl;
    cur[b * NCELL + t * 32 + j] = excl;
    excl += c[j];
  }
  if (t == 1023) start[b * (NCELL + 1) + NCELL] = excl;
}

__global__ __launch_bounds__(256) void k_scatter(const float* __restrict__ points,
                                                 const int* __restrict__ mask,
                                                 int* __restrict__ cur,
                                                 float4* __restrict__ sorted) {
  const int t = blockIdx.x * 256 + threadIdx.x;
  const int b = t >> 13;
  const int i = t & (N_PTS - 1);
  const float* P = points + (size_t)b * N_PTS * 3;
  const float x = P[3 * i + 0], y = P[3 * i + 1], z = P[3 * i + 2];
  const int cell = (cellOf(z) * GDIM + cellOf(y)) * GDIM + cellOf(x);
  const int pos = atomicAdd(&cur[b * NCELL + cell], 1);
  const unsigned wb = (unsigned)i | ((mask[b * N_PTS + i] != 0) ? 0x80000000u : 0u);
  sorted[(size_t)b * N_PTS + pos] = make_float4(x, y, z, __uint_as_float(wb));
}

// ---------------------------------------------------------------------------
// Kernel C: collect-then-sort, ONE WAVE per block, NSPLIT=4 blocks/supercell.
// Block `part` handles query slots q0 = part*4 + 16m (4 slots/pass, 16
// lanes/query). Certified-radius logic identical to R7/R8 (validated exact).
__global__ __launch_bounds__(64) void k_collect(const float* __restrict__ points,
                                                const float4* __restrict__ sorted,
                                                const int* __restrict__ start,
                                                const float* __restrict__ center,
                                                float* __restrict__ geom,
                                                int* __restrict__ list,
                                                int* __restrict__ listCnt,
                                                float DENS_T) {
  const int b    = blockIdx.y;
  const int sc   = blockIdx.x / NSPLIT;
  const int part = blockIdx.x % NSPLIT;
  const int sx = sc & 7, sy = (sc >> 3) & 7, sz = sc >> 6;
  const int lane = threadIdx.x;          // 0..63

  const int* ST = start + b * (NCELL + 1);
  const float4* SP = sorted + (size_t)b * N_PTS;

  const int x0 = SUP * sx, x1 = SUP * sx + SUP - 1;
  const int y0 = SUP * sy, y1 = SUP * sy + SUP - 1;
  const int z0 = SUP * sz, z1 = SUP * sz + SUP - 1;
  const int hx0 = max(x0 - 3, 0), hx1 = min(x1 + 3, GDIM - 1);
  const int hy0 = max(y0 - 3, 0), hy1 = min(y1 + 3, GDIM - 1);
  const int hz0 = max(z0 - 3, 0), hz1 = min(z1 + 3, GDIM - 1);
  const int yc = hy1 - hy0 + 1;               // <=10
  const int R  = (hz1 - hz0 + 1) * yc;        // <=100

  __shared__ int    rs[MAXROWS], rp[MAXROWS + 1];
  __shared__ int    qs_[16], qp_[17];
  __shared__ float4 pts4[SCAP];
  __shared__ u64    lbuf[64 * LSTR];

  // query rows: exactly 16 (4 z x 4 y); lane<16 owns row `lane`
  {
    int qlen = 0, qst = 0;
    if (lane < 16) {
      const int z = z0 + (lane >> 2), y = y0 + (lane & 3);
      const int base = (z * GDIM + y) * GDIM;
      qst  = ST[base + x0];
      qlen = ST[base + x1 + 1] - qst;
    }
    int inc = qlen;
    for (int off = 1; off < 64; off <<= 1) { int v = __shfl_up(inc, off); if (lane >= off) inc += v; }
    if (lane < 16) { qs_[lane] = qst; qp_[lane] = inc - qlen; }
    if (lane == 63) qp_[16] = inc;
  }
  // halo rows: 2 per lane, in row order
  {
    int len[2] = {0, 0}, st2[2] = {0, 0};
#pragma unroll
    for (int k = 0; k < 2; ++k) {
      const int r = lane * 2 + k;
      if (r < R) {
        const int z = hz0 + r / yc, y = hy0 + r % yc;
        const int base = (z * GDIM + y) * GDIM;
        st2[k] = ST[base + hx0];
        len[k] = ST[base + hx1 + 1] - st2[k];
      }
    }
    int sum = len[0] + len[1];
    int inc = sum;
    for (int off = 1; off < 64; off <<= 1) { int v = __shfl_up(inc, off); if (lane >= off) inc += v; }
    int exc = inc - sum;
#pragma unroll
    for (int k = 0; k < 2; ++k) {
      const int r = lane * 2 + k;
      if (r < R) { rs[r] = st2[k]; rp[r] = exc; }
      exc += len[k];
    }
    if (lane == 63) rp[R] = inc;
  }
  __syncthreads();

  const int C    = rp[R];
  const int qtot = qp_[16];
  if (qtot == 0) return;

  if (C > SCAP) {                 // astronomically rare: part 0 flags everything
    if (part == 0) {
      for (int t = lane; t < qtot; t += 64) {
        int lo = 0, hi = 15;
        while (lo < hi) { const int mid = (lo + hi + 1) >> 1; if (qp_[mid] <= t) lo = mid; else hi = mid - 1; }
        const int qglob = qs_[lo] + (t - qp_[lo]);
        const int pos = atomicAdd(listCnt, 1);
        list[pos] = (b << 13) | qglob;
      }
    }
    return;
  }

  // stage halo: lane owns rows r = lane, lane+64 (no binary search)
  for (int r = lane; r < R; r += 64) {
    const int st = rs[r], base = rp[r], len = rp[r + 1] - base;
    for (int t = 0; t < len; ++t) pts4[base + t] = SP[st + t];
  }
  __syncthreads();

  // supercell-uniform clamp flags
  const bool cxl = (x0 - 3 < 0), cxh = (x1 + 3 > GDIM - 1);
  const bool cyl = (y0 - 3 < 0), cyh = (y1 + 3 > GDIM - 1);
  const bool czl = (z0 - 3 < 0), czh = (z1 + 3 > GDIM - 1);

  const float4 ctr = reinterpret_cast<const float4*>(center)[b];
  const float* P = points + (size_t)b * N_PTS * 3;
  const int sub = lane & 15;    // 16 lanes per query
  const int gq  = lane >> 4;    // 4 query slots per pass

  for (int q0 = part * 4; q0 < qtot; q0 += NSPLIT * 4) {
    const int myq = q0 + gq;
    const bool act = (myq < qtot);
    const int mq = act ? myq : 0;
    int lo = 0, hi = 15;
    while (lo < hi) { const int mid = (lo + hi + 1) >> 1; if (qp_[mid] <= mq) lo = mid; else hi = mid - 1; }
    const int qglob = qs_[lo] + (mq - qp_[lo]);
    const float4 qp4 = SP[qglob];
    const int qidx = (int)(__float_as_uint(qp4.w) & 0x7FFFFFFFu);
    const float px = qp4.x, py = qp4.y, pz = qp4.z;
    const float sqq = sq3(px, py, pz);

    // certified radius (distance to non-clamped halo faces; clamped = domain edge = inf)
    const float mxl = cxl ? 1e9f : __fsub_rn(px, (float)hx0 * HCELL);
    const float mxh = cxh ? 1e9f : __fsub_rn((float)(hx1 + 1) * HCELL, px);
    const float myl = cyl ? 1e9f : __fsub_rn(py, (float)hy0 * HCELL);
    const float myh = cyh ? 1e9f : __fsub_rn((float)(hy1 + 1) * HCELL, py);
    const float mzl = czl ? 1e9f : __fsub_rn(pz, (float)hz0 * HCELL);
    const float mzh = czh ? 1e9f : __fsub_rn((float)(hz1 + 1) * HCELL, pz);
    const float gr = fminf(fminf(fminf(mxl, mxh), fminf(myl, myh)), fminf(mzl, mzh));
    // density-adaptive target radius (ball-clip model)
    const float fx = 0.5f * (1.0f + fminf(fminf(px, 1.0f - px) * (1.0f / 0.0935f), 1.0f));
    const float fy = 0.5f * (1.0f + fminf(fminf(py, 1.0f - py) * (1.0f / 0.0935f), 1.0f));
    const float fz = 0.5f * (1.0f + fminf(fminf(pz, 1.0f - pz) * (1.0f / 0.0935f), 1.0f));
    const float rT = 0.0935f * cbrtf(1.0f / (fx * fy * fz));
    const float cR = fminf(gr, rT);
    const float cT2 = cR * cR;
    const float certR = cR * 0.999f;

    int cnt = 0;
    u64* myb = &lbuf[lane * LSTR];
#pragma unroll 2
    for (int j = sub; j < C; j += 16) {
      const float4 tp = pts4[j];                      // 16 distinct addrs, conflict-free
      const float sqc = sq3(tp.x, tp.y, tp.z);
      const float dot = __fmaf_rn(pz, tp.z, __fmaf_rn(py, tp.y, __fmul_rn(px, tp.x)));
      const float d2  = __fsub_rn(__fadd_rn(sqq, sqc), __fmul_rn(2.0f, dot));
      const float d2c = fmaxf(d2, 0.0f);
      if (d2c < cT2) {
        if (cnt < LCAP) {
          const unsigned wb = __float_as_uint(tp.w);
          myb[cnt] = ((u64)__float_as_uint(d2c) << 32)
                   | (u64)(((wb & 0x7FFFFFFFu) << 1) | (wb >> 31));
        }
        ++cnt;
      }
    }

    u64 best[11];
#pragma unroll
    for (int j = 0; j < 11; ++j) best[j] = ~0ull;
    float dens = 0.0f;
    const int m = min(cnt, LCAP);
    for (int i = 0; i < m; ++i) {
      const u64 e = myb[i];
      if ((e & 1ull) && __uint_as_float((unsigned)(e >> 32)) < DENS_T) dens += 1.0f;
      if (e < best[10]) insert11(best, e);
    }
    int cntg = cnt;
    int over = (cnt > LCAP) ? 1 : 0;
    // 4-step butterfly merge within the 16-lane group
#pragma unroll
    for (int s = 1; s < 16; s <<= 1) {
      dens += __shfl_xor(dens, s);
      cntg += __shfl_xor(cntg, s);
      over |= __shfl_xor(over, s);
      u64 ok[11];
#pragma unroll
      for (int j = 0; j < 11; ++j) ok[j] = __shfl_xor(best[j], s);
#pragma unroll
      for (int j = 0; j < 11; ++j) {
        if (ok[j] < best[10]) insert11(best, ok[j]); else break;
      }
    }

    if (act && sub == 0) {
      const float dist9 = sqrtf(__uint_as_float((unsigned)(best[9] >> 32)));
      bool bad = (over != 0) || (cntg < 10) || !(dist9 < certR);
      if (cntg >= 11) {
        const float dist10 = sqrtf(__uint_as_float((unsigned)(best[10] >> 32)));
        bad = bad || (dist10 == dist9);
      }
      if (bad) {
        const int pos = atomicAdd(listCnt, 1);
        list[pos] = (b << 13) | qglob;
      } else {
        int idxs[10];
#pragma unroll
        for (int j = 0; j < 10; ++j) idxs[j] = (int)(((unsigned)best[j]) >> 1);
        geom_epilogue(P, idxs, dens, px, py, pz, ctr,
                      geom + ((size_t)b * N_PTS + qidx) * 6);
      }
    }
  }
}

// ---------------------------------------------------------------------------
// Tier-2: one WAVE per flagged query, 4 waves per block (grid-stride).
__global__ __launch_bounds__(256) void k_wavefb(const float* __restrict__ points,
                                                const float4* __restrict__ sorted,
                                                const int* __restrict__ start,
                                                const float* __restrict__ center,
                                                float* __restrict__ geom,
                                                int* __restrict__ flags2,
                                                const int* __restrict__ list,
                                                const int* __restrict__ listCnt) {
  const int lane = threadIdx.x & 63;
  const int wid  = threadIdx.x >> 6;
  const int n = *listCnt;
  for (int it = blockIdx.x * 4 + wid; it < n; it += gridDim.x * 4) {
    const int e = list[it];
    const int b = e >> 13, qs = e & (N_PTS - 1);
    const float4* SP = sorted + (size_t)b * N_PTS;
    const int* ST = start + b * (NCELL + 1);
    const float4 qp = SP[qs];
    const int qidx = (int)(__float_as_uint(qp.w) & 0x7FFFFFFFu);
    const float px = qp.x, py = qp.y, pz = qp.z;
    const float sqq = sq3(px, py, pz);
    const int cx = cellOf(px), cy = cellOf(py), cz = cellOf(pz);
    const int xlo = max(cx - 8, 0), xhi = min(cx + 8, GDIM - 1);
    const int ylo = max(cy - 8, 0), yhi = min(cy + 8, GDIM - 1);
    const int zlo = max(cz - 8, 0), zhi = min(cz + 8, GDIM - 1);
    const int ycw = yhi - ylo + 1;
    const int Rw = (zhi - zlo + 1) * ycw;

    u64 best[10];
#pragma unroll
    for (int j = 0; j < 10; ++j) best[j] = ((u64)0x7F800000u << 32) | 0xFFFFFFFFu;
    float dens = 0.0f;

    for (int r = lane; r < Rw; r += 64) {
      const int z = zlo + r / ycw, y = ylo + r % ycw;
      const int base = (z * GDIM + y) * GDIM;
      const int j0 = ST[base + xlo], j1 = ST[base + xhi + 1];
      for (int j = j0; j < j1; ++j) {
        const float4 tp = SP[j];
        const unsigned wb = __float_as_uint(tp.w);
        const float sqc = sq3(tp.x, tp.y, tp.z);
        const float dot = __fmaf_rn(pz, tp.z, __fmaf_rn(py, tp.y, __fmul_rn(px, tp.x)));
        const float d2  = __fsub_rn(__fadd_rn(sqq, sqc), __fmul_rn(2.0f, dot));
        const float dist = sqrtf(fmaxf(d2, 0.0f));
        if ((dist < RADIUS_F) && (wb & 0x80000000u)) dens += 1.0f;
        const u64 key = ((u64)__float_as_uint(dist) << 32) | (wb & 0x7FFFFFFFu);
        if (key < best[9]) insert10(best, key);
      }
    }
#pragma unroll
    for (int s = 1; s < 64; s <<= 1) {
      dens += __shfl_xor(dens, s);
      u64 ok[10];
#pragma unroll
      for (int j = 0; j < 10; ++j) ok[j] = __shfl_xor(best[j], s);
#pragma unroll
      for (int j = 0; j < 10; ++j) {
        if (ok[j] < best[9]) insert10(best, ok[j]); else break;
      }
    }
    if (lane == 0) {
      const float dist9 = __uint_as_float((unsigned)(best[9] >> 32));
      if (dist9 < 0.2494f) {
        const float4 ctr = reinterpret_cast<const float4*>(center)[b];
        const float* P = points + (size_t)b * N_PTS * 3;
        int idxs[10];
#pragma unroll
        for (int j = 0; j < 10; ++j) idxs[j] = (int)(((unsigned)best[j]) & 0x7FFFFFFFu);
        geom_epilogue(P, idxs, dens, px, py, pz, ctr, geom + ((size_t)b * N_PTS + qidx) * 6);
      } else {
        flags2[b * N_PTS + qs] = 1;
      }
    }
  }
}

// ---------------------------------------------------------------------------
// Tier-3: exact (dist,idx) ring-scan, gated on flags2 (runs for ~0 queries)
__global__ __launch_bounds__(256) void k_fallback(const float* __restrict__ points,
                                                  const float4* __restrict__ sorted,
                                                  const int* __restrict__ start,
                                                  const float* __restrict__ center,
                                                  float* __restrict__ geom,
                                                  const int* __restrict__ flags2) {
  const int b = blockIdx.y;
  const int qs = blockIdx.x * 256 + threadIdx.x;
  if (flags2[b * N_PTS + qs] == 0) return;
  const float4 qp = sorted[(size_t)b * N_PTS + qs];
  const unsigned qw = __float_as_uint(qp.w);
  const int qidx = (int)(qw & 0x7FFFFFFFu);

  const float px = qp.x, py = qp.y, pz = qp.z;
  const float sqq = sq3(px, py, pz);
  const int cx = cellOf(px), cy = cellOf(py), cz = cellOf(pz);

  const int* ST = start + b * (NCELL + 1);
  const float4* SP = sorted + (size_t)b * N_PTS;

  u64 best[10];
#pragma unroll
  for (int j = 0; j < 10; ++j) best[j] = ((u64)0x7F800000u << 32) | 0xFFFFFFFFu;
  float dens = 0.0f;

  for (int rho = 0; rho < GDIM; ++rho) {
    const int zlo = max(cz - rho, 0), zhi = min(cz + rho, GDIM - 1);
    const int ylo = max(cy - rho, 0), yhi = min(cy + rho, GDIM - 1);
    for (int z = zlo; z <= zhi; ++z) {
      const int adz = abs(z - cz);
      for (int y = ylo; y <= yhi; ++y) {
        const int ady = abs(y - cy);
        const int m2 = max(adz, ady);
        int ja, jb;
        int ja2 = 0, jb2 = 0;
        const int rowBase = (z * GDIM + y) * GDIM;
        if (m2 == rho) {
          const int xa = max(cx - rho, 0), xb = min(cx + rho, GDIM - 1);
          ja = ST[rowBase + xa]; jb = ST[rowBase + xb + 1];
        } else {
          ja = jb = 0;
          if (cx - rho >= 0)        { ja = ST[rowBase + cx - rho]; jb = ST[rowBase + cx - rho + 1]; }
          if (cx + rho <= GDIM - 1) { ja2 = ST[rowBase + cx + rho]; jb2 = ST[rowBase + cx + rho + 1]; }
        }
#pragma unroll 1
        for (int pass = 0; pass < 2; ++pass) {
          const int j0 = pass ? ja2 : ja;
          const int j1 = pass ? jb2 : jb;
          for (int j = j0; j < j1; ++j) {
            const float4 tp = SP[j];
            const unsigned wb = __float_as_uint(tp.w);
            const float sqc = sq3(tp.x, tp.y, tp.z);
            const float dot = __fmaf_rn(pz, tp.z, __fmaf_rn(py, tp.y, __fmul_rn(px, tp.x)));
            const float d2  = __fsub_rn(__fadd_rn(sqq, sqc), __fmul_rn(2.0f, dot));
            const float dist = sqrtf(fmaxf(d2, 0.0f));
            if ((dist < RADIUS_F) && (wb & 0x80000000u)) dens += 1.0f;
            const u64 key = ((u64)__float_as_uint(dist) << 32) | (wb & 0x7FFFFFFFu);
            if (key < best[9]) insert10(best, key);
          }
        }
      }
    }
    if (rho >= 1) {
      const float dist9 = __uint_as_float((unsigned)(best[9] >> 32));
      if (dist9 < (float)rho * HCELL * 0.999f) break;
    }
  }

  const float4 ctr = reinterpret_cast<const float4*>(center)[b];
  const float* P = points + (size_t)b * N_PTS * 3;
  int idxs[10];
#pragma unroll
  for (int j = 0; j < 10; ++j) idxs[j] = (int)(((unsigned)best[j]) & 0x7FFFFFFFu);
  geom_epilogue(P, idxs, dens, px, py, pz, ctr, geom + ((size_t)b * N_PTS + qidx) * 6);
}

// ---------------------------------------------------------------------------
// Kernel 3: fused 2-layer MLP with W staged in LDS (unchanged from R8).
__global__ __launch_bounds__(256) void k_mlp(const float* __restrict__ features,
                                             const float* __restrict__ geom,
                                             const float* __restrict__ W1,
                                             const float* __restrict__ b1,
                                             const float* __restrict__ W2,
                                             const float* __restrict__ b2,
                                             float* __restrict__ out) {
  __shared__ float Wbuf[ODIM * ODIM];        // 64 KB (W2-sized; W1 uses first 70 rows)
  __shared__ float A[64][71];
  __shared__ float H[64][133];
  const int tid = threadIdx.x;
  const int row0 = blockIdx.x * 64;

  {
    const int r = tid >> 2, f4 = (tid & 3) * 16;   // 4 float4 per thread
#pragma unroll
    for (int j = 0; j < 4; ++j) {
      const float4 v = *reinterpret_cast<const float4*>(
          &features[(size_t)(row0 + r) * IN_DIM + f4 + j * 4]);
      A[r][f4 + 4 * j + 0] = v.x; A[r][f4 + 4 * j + 1] = v.y;
      A[r][f4 + 4 * j + 2] = v.z; A[r][f4 + 4 * j + 3] = v.w;
    }
  }
  for (int i = tid; i < 64 * 6; i += 256) {
    const int r = i / 6, k = i % 6;
    A[r][IN_DIM + k] = geom[(size_t)(row0 + r) * 6 + k];
  }
  for (int i = tid; i < D_IN * ODIM / 4; i += 256) {
    const float4 v = reinterpret_cast<const float4*>(W1)[i];
    Wbuf[4 * i + 0] = v.x; Wbuf[4 * i + 1] = v.y;
    Wbuf[4 * i + 2] = v.z; Wbuf[4 * i + 3] = v.w;
  }
  __syncthreads();

  const int rg = (tid >> 4) * 4;    // 4 rows: rg..rg+3
  const int c  = (tid & 15) * 8;    // 8 cols

  float acc[4][8];
#pragma unroll
  for (int i = 0; i < 4; ++i)
#pragma unroll
    for (int j = 0; j < 8; ++j) acc[i][j] = 0.0f;

#pragma unroll 2
  for (int k = 0; k < D_IN; ++k) {
    float a[4];
#pragma unroll
    for (int i = 0; i < 4; ++i) a[i] = A[rg + i][k];
    const float4 w0 = *reinterpret_cast<const float4*>(&Wbuf[k * ODIM + c]);
    const float4 w1 = *reinterpret_cast<const float4*>(&Wbuf[k * ODIM + c + 4]);
    const float w[8] = {w0.x, w0.y, w0.z, w0.w, w1.x, w1.y, w1.z, w1.w};
#pragma unroll
    for (int i = 0; i < 4; ++i)
#pragma unroll
      for (int j = 0; j < 8; ++j) acc[i][j] = fmaf(a[i], w[j], acc[i][j]);
  }
  __syncthreads();                     // layer-1 reads of Wbuf done

  {
    const float4 bb0 = *reinterpret_cast<const float4*>(&b1[c]);
    const float4 bb1 = *reinterpret_cast<const float4*>(&b1[c + 4]);
    const float bb[8] = {bb0.x, bb0.y, bb0.z, bb0.w, bb1.x, bb1.y, bb1.z, bb1.w};
#pragma unroll
    for (int i = 0; i < 4; ++i) {
#pragma unroll
      for (int j = 0; j < 8; ++j) H[rg + i][c + j] = fmaxf(acc[i][j] + bb[j], 0.0f);
    }
  }
  for (int i = tid; i < ODIM * ODIM / 4; i += 256) {
    const float4 v = reinterpret_cast<const float4*>(W2)[i];
    Wbuf[4 * i + 0] = v.x; Wbuf[4 * i + 1] = v.y;
    Wbuf[4 * i + 2] = v.z; Wbuf[4 * i + 3] = v.w;
  }
  __syncthreads();

#pragma unroll
  for (int i = 0; i < 4; ++i)
#pragma unroll
    for (int j = 0; j < 8; ++j) acc[i][j] = 0.0f;

#pragma unroll 2
  for (int k = 0; k < ODIM; ++k) {
    float a[4];
#pragma unroll
    for (int i = 0; i < 4; ++i) a[i] = H[rg + i][k];
    const float4 w0 = *reinterpret_cast<const float4*>(&Wbuf[k * ODIM + c]);
    const float4 w1 = *reinterpret_cast<const float4*>(&Wbuf[k * ODIM + c + 4]);
    const float w[8] = {w0.x, w0.y, w0.z, w0.w, w1.x, w1.y, w1.z, w1.w};
#pragma unroll
    for (int i = 0; i < 4; ++i)
#pragma unroll
      for (int j = 0; j < 8; ++j) acc[i][j] = fmaf(a[i], w[j], acc[i][j]);
  }
  {
    const float4 bb0 = *reinterpret_cast<const float4*>(&b2[c]);
    const float4 bb1 = *reinterpret_cast<const float4*>(&b2[c + 4]);
    const float bb[8] = {bb0.x, bb0.y, bb0.z, bb0.w, bb1.x, bb1.y, bb1.z, bb1.w};
#pragma unroll
    for (int i = 0; i < 4; ++i) {
      const size_t row = (size_t)(row0 + rg + i);
      float4 o0 = make_float4(fmaxf(acc[i][0] + bb[0], 0.f), fmaxf(acc[i][1] + bb[1], 0.f),
                              fmaxf(acc[i][2] + bb[2], 0.f), fmaxf(acc[i][3] + bb[3], 0.f));
      float4 o1 = make_float4(fmaxf(acc[i][4] + bb[4], 0.f), fmaxf(acc[i][5] + bb[5], 0.f),
                              fmaxf(acc[i][6] + bb[6], 0.f), fmaxf(acc[i][7] + bb[7], 0.f));
      *reinterpret_cast<float4*>(&out[row * ODIM + c]) = o0;
      *reinterpret_cast<float4*>(&out[row * ODIM + c + 4]) = o1;
    }
  }
}

// ---------------------------------------------------------------------------
extern "C" void kernel_launch(void* const* d_in, const int* in_sizes, int n_in,
                              void* d_out, int out_size, void* d_ws, size_t ws_size,
                              hipStream_t stream) {
  const float* points   = (const float*)d_in[0];
  const float* features = (const float*)d_in[1];
  const int*   mask     = (const int*)d_in[2];
  const float* W1       = (const float*)d_in[3];
  const float* b1       = (const float*)d_in[4];
  const float* W2       = (const float*)d_in[5];
  const float* b2       = (const float*)d_in[6];
  float* out = (float*)d_out;

  // exact density threshold: dist < R  <=>  d2c < DENS_T  (validated R4-R8)
  const double Rd   = (double)0.02f;
  const double midd = Rd - ldexp(1.0, -30);
  const double Td   = midd * midd;
  float densT = (float)Td;
  if ((double)densT <= Td) densT = nextafterf(densT, 1.0f);

  // ws layout (256B aligned). countBuf+flags2+listCnt+ctrAcc contiguous for one memset.
  char* w = (char*)d_ws;
  size_t off = 0;
  auto take = [&](size_t bytes) { char* p = w + off; off = (off + bytes + 255) & ~(size_t)255; return p; };
  float*  geomBuf   = (float*)take((size_t)NQ_ALL * 6 * 4);
  float*  centerBuf = (float*)take(2 * 16);
  char*   zero0     = (char*)take(0);
  int*    countBuf  = (int*)take((size_t)B_SZ * NCELL * 4);
  int*    flags2Buf = (int*)take((size_t)NQ_ALL * 4);
  int*    listCnt   = (int*)take(4);
  double* ctrAcc    = (double*)take((size_t)B_SZ * 4 * 8);
  char*   zero1     = (char*)take(0);
  int*    startBuf  = (int*)take((size_t)B_SZ * (NCELL + 1) * 4);
  int*    curBuf    = (int*)take((size_t)B_SZ * NCELL * 4);
  float4* sortedBuf = (float4*)take((size_t)B_SZ * N_PTS * 16);
  int*    listBuf   = (int*)take((size_t)NQ_ALL * 4);
  (void)ws_size;

  hipMemsetAsync(zero0, 0, (size_t)(zero1 - zero0), stream);
  k_build<<<NQ_ALL / 256, 256, 0, stream>>>(points, mask, countBuf, ctrAcc);
  k_scan<<<B_SZ, 1024, 0, stream>>>(countBuf, startBuf, curBuf, ctrAcc, centerBuf);
  k_scatter<<<NQ_ALL / 256, 256, 0, stream>>>(points, mask, curBuf, sortedBuf);
  k_collect<<<dim3(NSUPER * NSPLIT, B_SZ), 64, 0, stream>>>(points, sortedBuf, startBuf,
                                                            centerBuf, geomBuf, listBuf,
                                                            listCnt, densT);
  k_wavefb<<<512, 256, 0, stream>>>(points, sortedBuf, startBuf, centerBuf,
                                    geomBuf, flags2Buf, listBuf, listCnt);
  k_fallback<<<dim3(N_PTS / 256, B_SZ), 256, 0, stream>>>(points, sortedBuf, startBuf,
                                                          centerBuf, geomBuf, flags2Buf);
  k_mlp<<<NQ_ALL / 64, 256, 0, stream>>>(features, geomBuf, W1, b1, W2, b2, out);
}

// Round 10
// 188.585 us; speedup vs baseline: 1.1879x; 1.1879x over previous
//
#include <hip/hip_runtime.h>
#include <math.h>
#include <stdint.h>

#define B_SZ   2
#define N_PTS  8192
#define IN_DIM 64
#define D_IN   70          // 64 features + 6 geom
#define ODIM   128
#define NQ_ALL (B_SZ * N_PTS)
#define RADIUS_F 0.02f

#define GDIM  32
#define NCELL (GDIM * GDIM * GDIM)
#define HCELL 0.03125f     // 1/32, exact in f32

#define SUP     4                       // base cells per supercell axis (exact tiling)
#define NSUP_AX 8
#define NSUPER  (NSUP_AX * NSUP_AX * NSUP_AX)   // 512
#define SCAP    352                     // staged halo capacity
#define LCAP    16                      // per-lane collect buffer (8 lanes/query)
#define LSTR    17                      // padded stride (u64) -> spread banks
#define MAXROWS 100                     // 10x10 halo (z,y) rows max

typedef unsigned long long u64;

// ---------------------------------------------------------------------------
// sorted ascending top-11 insert, u32 keys (1-instr min/max per level)
__device__ __forceinline__ void ins11u(unsigned (&best)[11], unsigned key) {
#pragma unroll
  for (int j = 10; j >= 1; --j) {
    unsigned hi = max(best[j - 1], key);
    best[j] = min(best[j], hi);
  }
  best[0] = min(best[0], key);
}
__device__ __forceinline__ void insert10(u64 (&best)[10], u64 key) {
#pragma unroll
  for (int j = 9; j >= 1; --j) {
    u64 hi = (best[j - 1] > key) ? best[j - 1] : key;
    best[j] = (best[j] < hi) ? best[j] : hi;
  }
  best[0] = (best[0] < key) ? best[0] : key;
}

// exact f32 helpers matching the reference's op order (no contraction)
__device__ __forceinline__ float sq3(float x, float y, float z) {
  return __fadd_rn(__fadd_rn(__fmul_rn(x, x), __fmul_rn(y, y)), __fmul_rn(z, z));
}

__device__ __forceinline__ int cellOf(float v) {
  int c = (int)(v * 32.0f);            // v*32 is exact (power-of-2 scale)
  return min(max(c, 0), GDIM - 1);
}

// shared epilogue: covariance over the 10 NN (exact f64) + eigen + geometry
__device__ __forceinline__ void geom_epilogue(const float* __restrict__ P,
                                              const int (&idxs)[10], float dens,
                                              float px, float py, float pz,
                                              float4 ctr, float* __restrict__ g) {
  double c00 = 0, c01 = 0, c02 = 0, c11 = 0, c12 = 0, c22 = 0;
#pragma unroll
  for (int j = 0; j < 10; ++j) {
    const int idx = idxs[j];
    const float nx = P[3 * idx + 0], ny = P[3 * idx + 1], nz = P[3 * idx + 2];
    const float ex = __fsub_rn(nx, px);
    const float ey = __fsub_rn(ny, py);
    const float ez = __fsub_rn(nz, pz);
    c00 += (double)ex * ex; c01 += (double)ex * ey; c02 += (double)ex * ez;
    c11 += (double)ey * ey; c12 += (double)ey * ez; c22 += (double)ez * ez;
  }
  const double a00 = c00 / 10.0, a01 = c01 / 10.0, a02 = c02 / 10.0;
  const double a11 = c11 / 10.0, a12 = c12 / 10.0, a22 = c22 / 10.0;

  double p1 = a01 * a01 + a02 * a02 + a12 * a12;
  double qq = (a00 + a11 + a22) / 3.0;
  double p2 = (a00 - qq) * (a00 - qq) + (a11 - qq) * (a11 - qq) +
              (a22 - qq) * (a22 - qq) + 2.0 * p1;
  double ev0, ev2;
  if (p2 <= 1e-60) {
    ev0 = ev2 = qq;
  } else {
    double p = sqrt(p2 / 6.0);
    double invp = 1.0 / p;
    double b00 = (a00 - qq) * invp, b11 = (a11 - qq) * invp, b22 = (a22 - qq) * invp;
    double b01 = a01 * invp, b02 = a02 * invp, b12 = a12 * invp;
    double detB = b00 * (b11 * b22 - b12 * b12) - b01 * (b01 * b22 - b12 * b02) +
                  b02 * (b01 * b12 - b11 * b02);
    double r = 0.5 * detB;
    r = fmin(1.0, fmax(-1.0, r));
    double phi = acos(r) / 3.0;
    ev2 = qq + 2.0 * p * cos(phi);
    ev0 = qq + 2.0 * p * cos(phi + 2.0943951023931953);  // +2*pi/3
  }
  const float curv = (float)(ev0 / (ev2 + 1e-08));

  const bool on = ctr.w > 0.0f;
  const float rx = __fsub_rn(px, ctr.x);
  const float ry = __fsub_rn(py, ctr.y);
  const float rz = __fsub_rn(pz, ctr.z);
  const float dist_c = sqrtf(sq3(rx, ry, rz));
  const float horiz  = sqrtf(__fadd_rn(__fmul_rn(rx, rx), __fmul_rn(ry, ry)));
  const float rad    = atan2f(ry, rx);

  g[0] = on ? dist_c : 0.0f;
  g[1] = on ? rz : 0.0f;
  g[2] = on ? horiz : 0.0f;
  g[3] = on ? dens : 0.0f;
  g[4] = on ? curv : 0.0f;
  g[5] = on ? rad : 0.0f;
}

// ---------------------------------------------------------------------------
// k_build: fused grid count + masked-centroid partial reduction.
__global__ __launch_bounds__(256) void k_build(const float* __restrict__ points,
                                               const int* __restrict__ mask,
                                               int* __restrict__ count,
                                               double* __restrict__ ctrAcc) {
  const int t = blockIdx.x * 256 + threadIdx.x;
  const int b = t >> 13;
  const int i = t & (N_PTS - 1);
  const float* P = points + (size_t)b * N_PTS * 3;
  const float x = P[3 * i + 0], y = P[3 * i + 1], z = P[3 * i + 2];
  atomicAdd(&count[b * NCELL + (cellOf(z) * GDIM + cellOf(y)) * GDIM + cellOf(x)], 1);

  const bool m = mask[b * N_PTS + i] != 0;
  double vx = m ? (double)x : 0.0, vy = m ? (double)y : 0.0;
  double vz = m ? (double)z : 0.0, vc = m ? 1.0 : 0.0;
#pragma unroll
  for (int s = 1; s < 64; s <<= 1) {
    vx += __shfl_xor(vx, s); vy += __shfl_xor(vy, s);
    vz += __shfl_xor(vz, s); vc += __shfl_xor(vc, s);
  }
  __shared__ double sh[4][4];
  const int w = threadIdx.x >> 6;
  if ((threadIdx.x & 63) == 0) { sh[0][w] = vx; sh[1][w] = vy; sh[2][w] = vz; sh[3][w] = vc; }
  __syncthreads();
  if (threadIdx.x == 0) {
    atomicAdd(&ctrAcc[b * 4 + 0], sh[0][0] + sh[0][1] + sh[0][2] + sh[0][3]);
    atomicAdd(&ctrAcc[b * 4 + 1], sh[1][0] + sh[1][1] + sh[1][2] + sh[1][3]);
    atomicAdd(&ctrAcc[b * 4 + 2], sh[2][0] + sh[2][1] + sh[2][2] + sh[2][3]);
    atomicAdd(&ctrAcc[b * 4 + 3], sh[3][0] + sh[3][1] + sh[3][2] + sh[3][3]);
  }
}

// one block of 1024 threads per batch; exclusive scan of 32768 counts.
__global__ __launch_bounds__(1024) void k_scan(const int* __restrict__ count,
                                               int* __restrict__ start,
                                               int* __restrict__ cur,
                                               const double* __restrict__ ctrAcc,
                                               float* __restrict__ centerOut) {
  const int b = blockIdx.x;
  const int t = threadIdx.x;
  if (t == 0) {
    const float cf = (float)ctrAcc[b * 4 + 3];
    const float div = fmaxf(cf, 1.0f);
    centerOut[b * 4 + 0] = (float)ctrAcc[b * 4 + 0] / div;
    centerOut[b * 4 + 1] = (float)ctrAcc[b * 4 + 1] / div;
    centerOut[b * 4 + 2] = (float)ctrAcc[b * 4 + 2] / div;
    centerOut[b * 4 + 3] = (cf > 0.0f) ? 1.0f : 0.0f;
  }
  int c[32]; int sum = 0;
#pragma unroll
  for (int j = 0; j < 32; ++j) { c[j] = count[b * NCELL + t * 32 + j]; sum += c[j]; }
  __shared__ int s[1024];
  s[t] = sum;
  __syncthreads();
  for (int off = 1; off < 1024; off <<= 1) {
    int v = (t >= off) ? s[t - off] : 0;
    __syncthreads();
    if (t >= off) s[t] += v;
    __syncthreads();
  }
  int excl = (t > 0) ? s[t - 1] : 0;
#pragma unroll
  for (int j = 0; j < 32; ++j) {
    start[b * (NCELL + 1) + t * 32 + j] = excl;
    cur[b * NCELL + t * 32 + j] = excl;
    excl += c[j];
  }
  if (t == 1023) start[b * (NCELL + 1) + NCELL] = excl;
}

__global__ __launch_bounds__(256) void k_scatter(const float* __restrict__ points,
                                                 const int* __restrict__ mask,
                                                 int* __restrict__ cur,
                                                 float4* __restrict__ sorted) {
  const int t = blockIdx.x * 256 + threadIdx.x;
  const int b = t >> 13;
  const int i = t & (N_PTS - 1);
  const float* P = points + (size_t)b * N_PTS * 3;
  const float x = P[3 * i + 0], y = P[3 * i + 1], z = P[3 * i + 2];
  const int cell = (cellOf(z) * GDIM + cellOf(y)) * GDIM + cellOf(x);
  const int pos = atomicAdd(&cur[b * NCELL + cell], 1);
  const unsigned wb = (unsigned)i | ((mask[b * N_PTS + i] != 0) ? 0x80000000u : 0u);
  sorted[(size_t)b * N_PTS + pos] = make_float4(x, y, z, __uint_as_float(wb));
}

// ---------------------------------------------------------------------------
// Kernel C: collect + u32-key top-11 select. 128 threads (2 waves), 8 lanes
// per query. Writes 48-B records (10 idxs + dens + flag); NO f64 epilogue here
// (k_geom2 does it full-SIMT). Certified-radius logic identical to R7-R9.
__global__ __launch_bounds__(128) void k_collect(const float4* __restrict__ sorted,
                                                 const int* __restrict__ start,
                                                 int* __restrict__ recBuf,
                                                 int* __restrict__ list,
                                                 int* __restrict__ listCnt,
                                                 float DENS_T) {
  const int b  = blockIdx.y;
  const int sc = blockIdx.x;
  const int sx = sc & 7, sy = (sc >> 3) & 7, sz = sc >> 6;
  const int tid = threadIdx.x;           // 0..127

  const int* ST = start + b * (NCELL + 1);
  const float4* SP = sorted + (size_t)b * N_PTS;

  const int x0 = SUP * sx, x1 = SUP * sx + SUP - 1;
  const int y0 = SUP * sy, y1 = SUP * sy + SUP - 1;
  const int z0 = SUP * sz, z1 = SUP * sz + SUP - 1;
  const int hx0 = max(x0 - 3, 0), hx1 = min(x1 + 3, GDIM - 1);
  const int hy0 = max(y0 - 3, 0), hy1 = min(y1 + 3, GDIM - 1);
  const int hz0 = max(z0 - 3, 0), hz1 = min(z1 + 3, GDIM - 1);
  const int yc = hy1 - hy0 + 1;               // <=10
  const int R  = (hz1 - hz0 + 1) * yc;        // <=100

  __shared__ int    rs[MAXROWS], rp[MAXROWS + 1];
  __shared__ int    qs_[16], qp_[17];
  __shared__ float4 pts4[SCAP];
  __shared__ u64    lbuf[128 * LSTR];
  __shared__ int    gslot[16][12];

  if (tid < 64) {
    {
      int qlen = 0, qst = 0;
      if (tid < 16) {
        const int z = z0 + (tid >> 2), y = y0 + (tid & 3);
        const int base = (z * GDIM + y) * GDIM;
        qst  = ST[base + x0];
        qlen = ST[base + x1 + 1] - qst;
      }
      int inc = qlen;
      for (int off = 1; off < 64; off <<= 1) { int v = __shfl_up(inc, off); if (tid >= off) inc += v; }
      if (tid < 16) { qs_[tid] = qst; qp_[tid] = inc - qlen; }
      if (tid == 63) qp_[16] = inc;
    }
    {
      int len[2] = {0, 0}, st2[2] = {0, 0};
#pragma unroll
      for (int k = 0; k < 2; ++k) {
        const int r = tid * 2 + k;
        if (r < R) {
          const int z = hz0 + r / yc, y = hy0 + r % yc;
          const int base = (z * GDIM + y) * GDIM;
          st2[k] = ST[base + hx0];
          len[k] = ST[base + hx1 + 1] - st2[k];
        }
      }
      int sum = len[0] + len[1];
      int inc = sum;
      for (int off = 1; off < 64; off <<= 1) { int v = __shfl_up(inc, off); if (tid >= off) inc += v; }
      int exc = inc - sum;
#pragma unroll
      for (int k = 0; k < 2; ++k) {
        const int r = tid * 2 + k;
        if (r < R) { rs[r] = st2[k]; rp[r] = exc; }
        exc += len[k];
      }
      if (tid == 63) rp[R] = inc;
    }
  }
  __syncthreads();

  const int C    = rp[R];
  const int qtot = qp_[16];
  if (qtot == 0) return;

  if (C > SCAP) {                 // astronomically rare: all queries to tier-2
    for (int t = tid; t < qtot; t += 128) {
      int lo = 0, hi = 15;
      while (lo < hi) { const int mid = (lo + hi + 1) >> 1; if (qp_[mid] <= t) lo = mid; else hi = mid - 1; }
      const int qglob = qs_[lo] + (t - qp_[lo]);
      recBuf[((size_t)b * N_PTS + qglob) * 12 + 11] = 1;
      const int pos = atomicAdd(listCnt, 1);
      list[pos] = (b << 13) | qglob;
    }
    return;
  }

  for (int i = tid; i < C; i += 128) {   // stage halo
    int lo = 0, hi = R - 1;
    while (lo < hi) { const int mid = (lo + hi + 1) >> 1; if (rp[mid] <= i) lo = mid; else hi = mid - 1; }
    pts4[i] = SP[rs[lo] + (i - rp[lo])];
  }
  __syncthreads();

  // supercell-uniform clamp flags
  const bool cxl = (x0 - 3 < 0), cxh = (x1 + 3 > GDIM - 1);
  const bool cyl = (y0 - 3 < 0), cyh = (y1 + 3 > GDIM - 1);
  const bool czl = (z0 - 3 < 0), czh = (z1 + 3 > GDIM - 1);

  const int sub = tid & 7;      // 8 lanes per query
  const int gq  = tid >> 3;     // 16 query slots per pass
  const int g   = tid >> 3;     // group id 0..15 (per-block)

  for (int q0 = 0; q0 < qtot; q0 += 16) {
    const int myq = q0 + gq;
    const bool act = (myq < qtot);
    const int mq = act ? myq : 0;
    int lo = 0, hi = 15;
    while (lo < hi) { const int mid = (lo + hi + 1) >> 1; if (qp_[mid] <= mq) lo = mid; else hi = mid - 1; }
    const int qglob = qs_[lo] + (mq - qp_[lo]);
    const float4 qp4 = SP[qglob];
    const float px = qp4.x, py = qp4.y, pz = qp4.z;
    const float sqq = sq3(px, py, pz);

    // certified radius (distance to non-clamped halo faces; clamped = domain edge = inf)
    const float mxl = cxl ? 1e9f : __fsub_rn(px, (float)hx0 * HCELL);
    const float mxh = cxh ? 1e9f : __fsub_rn((float)(hx1 + 1) * HCELL, px);
    const float myl = cyl ? 1e9f : __fsub_rn(py, (float)hy0 * HCELL);
    const float myh = cyh ? 1e9f : __fsub_rn((float)(hy1 + 1) * HCELL, py);
    const float mzl = czl ? 1e9f : __fsub_rn(pz, (float)hz0 * HCELL);
    const float mzh = czh ? 1e9f : __fsub_rn((float)(hz1 + 1) * HCELL, pz);
    const float gr = fminf(fminf(fminf(mxl, mxh), fminf(myl, myh)), fminf(mzl, mzh));
    const float fx = 0.5f * (1.0f + fminf(fminf(px, 1.0f - px) * (1.0f / 0.0935f), 1.0f));
    const float fy = 0.5f * (1.0f + fminf(fminf(py, 1.0f - py) * (1.0f / 0.0935f), 1.0f));
    const float fz = 0.5f * (1.0f + fminf(fminf(pz, 1.0f - pz) * (1.0f / 0.0935f), 1.0f));
    const float rT = 0.0935f * cbrtf(1.0f / (fx * fy * fz));
    const float cR = fminf(gr, rT);
    const float cT2 = cR * cR;
    const float certR = cR * 0.999f;

    int cnt = 0;
    u64* myb = &lbuf[tid * LSTR];
#pragma unroll 4
    for (int j = sub; j < C; j += 8) {
      const float4 tp = pts4[j];                      // broadcast-friendly
      const float sqc = sq3(tp.x, tp.y, tp.z);
      const float dot = __fmaf_rn(pz, tp.z, __fmaf_rn(py, tp.y, __fmul_rn(px, tp.x)));
      const float d2  = __fsub_rn(__fadd_rn(sqq, sqc), __fmul_rn(2.0f, dot));
      const float d2c = fmaxf(d2, 0.0f);
      if (d2c < cT2) {
        if (cnt < LCAP) {
          const unsigned wb = __float_as_uint(tp.w);
          myb[cnt] = ((u64)__float_as_uint(d2c) << 32)
                   | (u64)(((wb & 0x7FFFFFFFu) << 1) | (wb >> 31));
        }
        ++cnt;
      }
    }

    // per-lane finalize (u32 d2 keys) + density
    unsigned best[11];
#pragma unroll
    for (int j = 0; j < 11; ++j) best[j] = 0xFFFFFFFFu;
    float dens = 0.0f;
    const int m = min(cnt, LCAP);
    for (int i = 0; i < m; ++i) {
      const u64 e = myb[i];
      const unsigned d2u = (unsigned)(e >> 32);
      if ((e & 1ull) && __uint_as_float(d2u) < DENS_T) dens += 1.0f;
      if (d2u < best[10]) ins11u(best, d2u);
    }
    int cntg = cnt;
    int over = (cnt > LCAP) ? 1 : 0;
    // 3-step butterfly merge (u32)
#pragma unroll
    for (int s = 1; s < 8; s <<= 1) {
      dens += __shfl_xor(dens, s);
      cntg += __shfl_xor(cntg, s);
      over |= __shfl_xor(over, s);
      unsigned ok[11];
#pragma unroll
      for (int j = 0; j < 11; ++j) ok[j] = __shfl_xor(best[j], s);
#pragma unroll
      for (int j = 0; j < 11; ++j) {
        if (ok[j] < best[10]) ins11u(best, ok[j]); else break;
      }
    }

    if (act) {
      const unsigned T9 = best[9];
      const float dist9 = sqrtf(__uint_as_float(T9));
      bool bad = (over != 0) || (cntg < 10) || !(dist9 < certR);
      if (cntg >= 11) bad = bad || (sqrtf(__uint_as_float(best[10])) == dist9);
      int* rec = recBuf + ((size_t)b * N_PTS + qglob) * 12;
      if (!bad) {
        // gather the 10 indices (d2bits <= T9, exactly 10 when unflagged)
        int mc = 0;
        for (int i = 0; i < m; ++i) if ((unsigned)(myb[i] >> 32) <= T9) ++mc;
        int pre = mc;
#pragma unroll
        for (int off = 1; off < 8; off <<= 1) { int v = __shfl_up(pre, off); if (sub >= off) pre += v; }
        int wp = pre - mc;
        for (int i = 0; i < m; ++i) {
          const u64 e = myb[i];
          if ((unsigned)(e >> 32) <= T9) { gslot[g][min(wp, 11)] = (int)(((unsigned)e) >> 1); ++wp; }
        }
        __builtin_amdgcn_wave_barrier();
        if (sub == 0) {
          int4 r0 = make_int4(gslot[g][0], gslot[g][1], gslot[g][2], gslot[g][3]);
          int4 r1 = make_int4(gslot[g][4], gslot[g][5], gslot[g][6], gslot[g][7]);
          int4 r2 = make_int4(gslot[g][8], gslot[g][9], __float_as_int(dens), 0);
          *reinterpret_cast<int4*>(rec + 0) = r0;
          *reinterpret_cast<int4*>(rec + 4) = r1;
          *reinterpret_cast<int4*>(rec + 8) = r2;
        }
        __builtin_amdgcn_wave_barrier();
      } else if (sub == 0) {
        rec[11] = 1;
        const int pos = atomicAdd(listCnt, 1);
        list[pos] = (b << 13) | qglob;
      }
    }
  }
}

// ---------------------------------------------------------------------------
// k_geom2: full-SIMT f64 eigen epilogue, 1 thread/query, gated on record flag.
__global__ __launch_bounds__(256) void k_geom2(const float* __restrict__ points,
                                               const float4* __restrict__ sorted,
                                               const float* __restrict__ center,
                                               const int* __restrict__ recBuf,
                                               float* __restrict__ geom) {
  const int t = blockIdx.x * 256 + threadIdx.x;
  const int b = t >> 13;
  const int qs = t & (N_PTS - 1);
  const int* rec = recBuf + (size_t)t * 12;
  if (rec[11] != 0) return;            // flagged: tier-2/3 own this query
  const float4 qp = sorted[(size_t)b * N_PTS + qs];
  const int qidx = (int)(__float_as_uint(qp.w) & 0x7FFFFFFFu);
  int idxs[10];
#pragma unroll
  for (int j = 0; j < 10; ++j) idxs[j] = rec[j];
  const float dens = __int_as_float(rec[10]);
  const float4 ctr = reinterpret_cast<const float4*>(center)[b];
  const float* P = points + (size_t)b * N_PTS * 3;
  geom_epilogue(P, idxs, dens, qp.x, qp.y, qp.z, ctr,
                geom + ((size_t)b * N_PTS + qidx) * 6);
}

// ---------------------------------------------------------------------------
// Tier-2: one WAVE per flagged query, 4 waves per block (grid-stride).
__global__ __launch_bounds__(256) void k_wavefb(const float* __restrict__ points,
                                                const float4* __restrict__ sorted,
                                                const int* __restrict__ start,
                                                const float* __restrict__ center,
                                                float* __restrict__ geom,
                                                int* __restrict__ flags2,
                                                const int* __restrict__ list,
                                                const int* __restrict__ listCnt) {
  const int lane = threadIdx.x & 63;
  const int wid  = threadIdx.x >> 6;
  const int n = *listCnt;
  for (int it = blockIdx.x * 4 + wid; it < n; it += gridDim.x * 4) {
    const int e = list[it];
    const int b = e >> 13, qs = e & (N_PTS - 1);
    const float4* SP = sorted + (size_t)b * N_PTS;
    const int* ST = start + b * (NCELL + 1);
    const float4 qp = SP[qs];
    const int qidx = (int)(__float_as_uint(qp.w) & 0x7FFFFFFFu);
    const float px = qp.x, py = qp.y, pz = qp.z;
    const float sqq = sq3(px, py, pz);
    const int cx = cellOf(px), cy = cellOf(py), cz = cellOf(pz);
    const int xlo = max(cx - 8, 0), xhi = min(cx + 8, GDIM - 1);
    const int ylo = max(cy - 8, 0), yhi = min(cy + 8, GDIM - 1);
    const int zlo = max(cz - 8, 0), zhi = min(cz + 8, GDIM - 1);
    const int ycw = yhi - ylo + 1;
    const int Rw = (zhi - zlo + 1) * ycw;

    u64 best[10];
#pragma unroll
    for (int j = 0; j < 10; ++j) best[j] = ((u64)0x7F800000u << 32) | 0xFFFFFFFFu;
    float dens = 0.0f;

    for (int r = lane; r < Rw; r += 64) {
      const int z = zlo + r / ycw, y = ylo + r % ycw;
      const int base = (z * GDIM + y) * GDIM;
      const int j0 = ST[base + xlo], j1 = ST[base + xhi + 1];
      for (int j = j0; j < j1; ++j) {
        const float4 tp = SP[j];
        const unsigned wb = __float_as_uint(tp.w);
        const float sqc = sq3(tp.x, tp.y, tp.z);
        const float dot = __fmaf_rn(pz, tp.z, __fmaf_rn(py, tp.y, __fmul_rn(px, tp.x)));
        const float d2  = __fsub_rn(__fadd_rn(sqq, sqc), __fmul_rn(2.0f, dot));
        const float dist = sqrtf(fmaxf(d2, 0.0f));
        if ((dist < RADIUS_F) && (wb & 0x80000000u)) dens += 1.0f;
        const u64 key = ((u64)__float_as_uint(dist) << 32) | (wb & 0x7FFFFFFFu);
        if (key < best[9]) insert10(best, key);
      }
    }
#pragma unroll
    for (int s = 1; s < 64; s <<= 1) {
      dens += __shfl_xor(dens, s);
      u64 ok[10];
#pragma unroll
      for (int j = 0; j < 10; ++j) ok[j] = __shfl_xor(best[j], s);
#pragma unroll
      for (int j = 0; j < 10; ++j) {
        if (ok[j] < best[9]) insert10(best, ok[j]); else break;
      }
    }
    if (lane == 0) {
      const float dist9 = __uint_as_float((unsigned)(best[9] >> 32));
      if (dist9 < 0.2494f) {
        const float4 ctr = reinterpret_cast<const float4*>(center)[b];
        const float* P = points + (size_t)b * N_PTS * 3;
        int idxs[10];
#pragma unroll
        for (int j = 0; j < 10; ++j) idxs[j] = (int)(((unsigned)best[j]) & 0x7FFFFFFFu);
        geom_epilogue(P, idxs, dens, px, py, pz, ctr, geom + ((size_t)b * N_PTS + qidx) * 6);
      } else {
        flags2[b * N_PTS + qs] = 1;
      }
    }
  }
}

// ---------------------------------------------------------------------------
// Tier-3: exact (dist,idx) ring-scan, gated on flags2 (runs for ~0 queries)
__global__ __launch_bounds__(256) void k_fallback(const float* __restrict__ points,
                                                  const float4* __restrict__ sorted,
                                                  const int* __restrict__ start,
                                                  const float* __restrict__ center,
                                                  float* __restrict__ geom,
                                                  const int* __restrict__ flags2) {
  const int b = blockIdx.y;
  const int qs = blockIdx.x * 256 + threadIdx.x;
  if (flags2[b * N_PTS + qs] == 0) return;
  const float4 qp = sorted[(size_t)b * N_PTS + qs];
  const unsigned qw = __float_as_uint(qp.w);
  const int qidx = (int)(qw & 0x7FFFFFFFu);

  const float px = qp.x, py = qp.y, pz = qp.z;
  const float sqq = sq3(px, py, pz);
  const int cx = cellOf(px), cy = cellOf(py), cz = cellOf(pz);

  const int* ST = start + b * (NCELL + 1);
  const float4* SP = sorted + (size_t)b * N_PTS;

  u64 best[10];
#pragma unroll
  for (int j = 0; j < 10; ++j) best[j] = ((u64)0x7F800000u << 32) | 0xFFFFFFFFu;
  float dens = 0.0f;

  for (int rho = 0; rho < GDIM; ++rho) {
    const int zlo = max(cz - rho, 0), zhi = min(cz + rho, GDIM - 1);
    const int ylo = max(cy - rho, 0), yhi = min(cy + rho, GDIM - 1);
    for (int z = zlo; z <= zhi; ++z) {
      const int adz = abs(z - cz);
      for (int y = ylo; y <= yhi; ++y) {
        const int ady = abs(y - cy);
        const int m2 = max(adz, ady);
        int ja, jb;
        int ja2 = 0, jb2 = 0;
        const int rowBase = (z * GDIM + y) * GDIM;
        if (m2 == rho) {
          const int xa = max(cx - rho, 0), xb = min(cx + rho, GDIM - 1);
          ja = ST[rowBase + xa]; jb = ST[rowBase + xb + 1];
        } else {
          ja = jb = 0;
          if (cx - rho >= 0)        { ja = ST[rowBase + cx - rho]; jb = ST[rowBase + cx - rho + 1]; }
          if (cx + rho <= GDIM - 1) { ja2 = ST[rowBase + cx + rho]; jb2 = ST[rowBase + cx + rho + 1]; }
        }
#pragma unroll 1
        for (int pass = 0; pass < 2; ++pass) {
          const int j0 = pass ? ja2 : ja;
          const int j1 = pass ? jb2 : jb;
          for (int j = j0; j < j1; ++j) {
            const float4 tp = SP[j];
            const unsigned wb = __float_as_uint(tp.w);
            const float sqc = sq3(tp.x, tp.y, tp.z);
            const float dot = __fmaf_rn(pz, tp.z, __fmaf_rn(py, tp.y, __fmul_rn(px, tp.x)));
            const float d2  = __fsub_rn(__fadd_rn(sqq, sqc), __fmul_rn(2.0f, dot));
            const float dist = sqrtf(fmaxf(d2, 0.0f));
            if ((dist < RADIUS_F) && (wb & 0x80000000u)) dens += 1.0f;
            const u64 key = ((u64)__float_as_uint(dist) << 32) | (wb & 0x7FFFFFFFu);
            if (key < best[9]) insert10(best, key);
          }
        }
      }
    }
    if (rho >= 1) {
      const float dist9 = __uint_as_float((unsigned)(best[9] >> 32));
      if (dist9 < (float)rho * HCELL * 0.999f) break;
    }
  }

  const float4 ctr = reinterpret_cast<const float4*>(center)[b];
  const float* P = points + (size_t)b * N_PTS * 3;
  int idxs[10];
#pragma unroll
  for (int j = 0; j < 10; ++j) idxs[j] = (int)(((unsigned)best[j]) & 0x7FFFFFFFu);
  geom_epilogue(P, idxs, dens, px, py, pz, ctr, geom + ((size_t)b * N_PTS + qidx) * 6);
}

// ---------------------------------------------------------------------------
// Kernel 3: fused 2-layer MLP with W staged in LDS (unchanged from R8).
__global__ __launch_bounds__(256) void k_mlp(const float* __restrict__ features,
                                             const float* __restrict__ geom,
                                             const float* __restrict__ W1,
                                             const float* __restrict__ b1,
                                             const float* __restrict__ W2,
                                             const float* __restrict__ b2,
                                             float* __restrict__ out) {
  __shared__ float Wbuf[ODIM * ODIM];        // 64 KB (W2-sized; W1 uses first 70 rows)
  __shared__ float A[64][71];
  __shared__ float H[64][133];
  const int tid = threadIdx.x;
  const int row0 = blockIdx.x * 64;

  {
    const int r = tid >> 2, f4 = (tid & 3) * 16;   // 4 float4 per thread
#pragma unroll
    for (int j = 0; j < 4; ++j) {
      const float4 v = *reinterpret_cast<const float4*>(
          &features[(size_t)(row0 + r) * IN_DIM + f4 + j * 4]);
      A[r][f4 + 4 * j + 0] = v.x; A[r][f4 + 4 * j + 1] = v.y;
      A[r][f4 + 4 * j + 2] = v.z; A[r][f4 + 4 * j + 3] = v.w;
    }
  }
  for (int i = tid; i < 64 * 6; i += 256) {
    const int r = i / 6, k = i % 6;
    A[r][IN_DIM + k] = geom[(size_t)(row0 + r) * 6 + k];
  }
  for (int i = tid; i < D_IN * ODIM / 4; i += 256) {
    const float4 v = reinterpret_cast<const float4*>(W1)[i];
    Wbuf[4 * i + 0] = v.x; Wbuf[4 * i + 1] = v.y;
    Wbuf[4 * i + 2] = v.z; Wbuf[4 * i + 3] = v.w;
  }
  __syncthreads();

  const int rg = (tid >> 4) * 4;    // 4 rows: rg..rg+3
  const int c  = (tid & 15) * 8;    // 8 cols

  float acc[4][8];
#pragma unroll
  for (int i = 0; i < 4; ++i)
#pragma unroll
    for (int j = 0; j < 8; ++j) acc[i][j] = 0.0f;

#pragma unroll 2
  for (int k = 0; k < D_IN; ++k) {
    float a[4];
#pragma unroll
    for (int i = 0; i < 4; ++i) a[i] = A[rg + i][k];
    const float4 w0 = *reinterpret_cast<const float4*>(&Wbuf[k * ODIM + c]);
    const float4 w1 = *reinterpret_cast<const float4*>(&Wbuf[k * ODIM + c + 4]);
    const float w[8] = {w0.x, w0.y, w0.z, w0.w, w1.x, w1.y, w1.z, w1.w};
#pragma unroll
    for (int i = 0; i < 4; ++i)
#pragma unroll
      for (int j = 0; j < 8; ++j) acc[i][j] = fmaf(a[i], w[j], acc[i][j]);
  }
  __syncthreads();                     // layer-1 reads of Wbuf done

  {
    const float4 bb0 = *reinterpret_cast<const float4*>(&b1[c]);
    const float4 bb1 = *reinterpret_cast<const float4*>(&b1[c + 4]);
    const float bb[8] = {bb0.x, bb0.y, bb0.z, bb0.w, bb1.x, bb1.y, bb1.z, bb1.w};
#pragma unroll
    for (int i = 0; i < 4; ++i) {
#pragma unroll
      for (int j = 0; j < 8; ++j) H[rg + i][c + j] = fmaxf(acc[i][j] + bb[j], 0.0f);
    }
  }
  for (int i = tid; i < ODIM * ODIM / 4; i += 256) {
    const float4 v = reinterpret_cast<const float4*>(W2)[i];
    Wbuf[4 * i + 0] = v.x; Wbuf[4 * i + 1] = v.y;
    Wbuf[4 * i + 2] = v.z; Wbuf[4 * i + 3] = v.w;
  }
  __syncthreads();

#pragma unroll
  for (int i = 0; i < 4; ++i)
#pragma unroll
    for (int j = 0; j < 8; ++j) acc[i][j] = 0.0f;

#pragma unroll 2
  for (int k = 0; k < ODIM; ++k) {
    float a[4];
#pragma unroll
    for (int i = 0; i < 4; ++i) a[i] = H[rg + i][k];
    const float4 w0 = *reinterpret_cast<const float4*>(&Wbuf[k * ODIM + c]);
    const float4 w1 = *reinterpret_cast<const float4*>(&Wbuf[k * ODIM + c + 4]);
    const float w[8] = {w0.x, w0.y, w0.z, w0.w, w1.x, w1.y, w1.z, w1.w};
#pragma unroll
    for (int i = 0; i < 4; ++i)
#pragma unroll
      for (int j = 0; j < 8; ++j) acc[i][j] = fmaf(a[i], w[j], acc[i][j]);
  }
  {
    const float4 bb0 = *reinterpret_cast<const float4*>(&b2[c]);
    const float4 bb1 = *reinterpret_cast<const float4*>(&b2[c + 4]);
    const float bb[8] = {bb0.x, bb0.y, bb0.z, bb0.w, bb1.x, bb1.y, bb1.z, bb1.w};
#pragma unroll
    for (int i = 0; i < 4; ++i) {
      const size_t row = (size_t)(row0 + rg + i);
      float4 o0 = make_float4(fmaxf(acc[i][0] + bb[0], 0.f), fmaxf(acc[i][1] + bb[1], 0.f),
                              fmaxf(acc[i][2] + bb[2], 0.f), fmaxf(acc[i][3] + bb[3], 0.f));
      float4 o1 = make_float4(fmaxf(acc[i][4] + bb[4], 0.f), fmaxf(acc[i][5] + bb[5], 0.f),
                              fmaxf(acc[i][6] + bb[6], 0.f), fmaxf(acc[i][7] + bb[7], 0.f));
      *reinterpret_cast<float4*>(&out[row * ODIM + c]) = o0;
      *reinterpret_cast<float4*>(&out[row * ODIM + c + 4]) = o1;
    }
  }
}

// ---------------------------------------------------------------------------
extern "C" void kernel_launch(void* const* d_in, const int* in_sizes, int n_in,
                              void* d_out, int out_size, void* d_ws, size_t ws_size,
                              hipStream_t stream) {
  const float* points   = (const float*)d_in[0];
  const float* features = (const float*)d_in[1];
  const int*   mask     = (const int*)d_in[2];
  const float* W1       = (const float*)d_in[3];
  const float* b1       = (const float*)d_in[4];
  const float* W2       = (const float*)d_in[5];
  const float* b2       = (const float*)d_in[6];
  float* out = (float*)d_out;

  // exact density threshold: dist < R  <=>  d2c < DENS_T  (validated R4-R9)
  const double Rd   = (double)0.02f;
  const double midd = Rd - ldexp(1.0, -30);
  const double Td   = midd * midd;
  float densT = (float)Td;
  if ((double)densT <= Td) densT = nextafterf(densT, 1.0f);

  // ws layout (256B aligned). countBuf+flags2+listCnt+ctrAcc contiguous for one memset.
  char* w = (char*)d_ws;
  size_t off = 0;
  auto take = [&](size_t bytes) { char* p = w + off; off = (off + bytes + 255) & ~(size_t)255; return p; };
  float*  geomBuf   = (float*)take((size_t)NQ_ALL * 6 * 4);
  float*  centerBuf = (float*)take(2 * 16);
  char*   zero0     = (char*)take(0);
  int*    countBuf  = (int*)take((size_t)B_SZ * NCELL * 4);
  int*    flags2Buf = (int*)take((size_t)NQ_ALL * 4);
  int*    listCnt   = (int*)take(4);
  double* ctrAcc    = (double*)take((size_t)B_SZ * 4 * 8);
  char*   zero1     = (char*)take(0);
  int*    startBuf  = (int*)take((size_t)B_SZ * (NCELL + 1) * 4);
  int*    curBuf    = (int*)take((size_t)B_SZ * NCELL * 4);
  float4* sortedBuf = (float4*)take((size_t)B_SZ * N_PTS * 16);
  int*    listBuf   = (int*)take((size_t)NQ_ALL * 4);
  int*    recBuf    = (int*)take((size_t)NQ_ALL * 12 * 4);
  (void)ws_size;

  hipMemsetAsync(zero0, 0, (size_t)(zero1 - zero0), stream);
  k_build<<<NQ_ALL / 256, 256, 0, stream>>>(points, mask, countBuf, ctrAcc);
  k_scan<<<B_SZ, 1024, 0, stream>>>(countBuf, startBuf, curBuf, ctrAcc, centerBuf);
  k_scatter<<<NQ_ALL / 256, 256, 0, stream>>>(points, mask, curBuf, sortedBuf);
  k_collect<<<dim3(NSUPER, B_SZ), 128, 0, stream>>>(sortedBuf, startBuf, recBuf,
                                                    listBuf, listCnt, densT);
  k_geom2<<<NQ_ALL / 256, 256, 0, stream>>>(points, sortedBuf, centerBuf, recBuf, geomBuf);
  k_wavefb<<<512, 256, 0, stream>>>(points, sortedBuf, startBuf, centerBuf,
                                    geomBuf, flags2Buf, listBuf, listCnt);
  k_fallback<<<dim3(N_PTS / 256, B_SZ), 256, 0, stream>>>(points, sortedBuf, startBuf,
                                                          centerBuf, geomBuf, flags2Buf);
  k_mlp<<<NQ_ALL / 64, 256, 0, stream>>>(features, geomBuf, W1, b1, W2, b2, out);
}